// Round 13
// baseline (838.909 us; speedup 1.0000x reference)
//
#include <hip/hip_runtime.h>
#include <hip/hip_bf16.h>
#include <stdint.h>

typedef __attribute__((ext_vector_type(8))) short bf16x8;
typedef __attribute__((ext_vector_type(4))) float f32x4;

#define LN_EPS 1e-5f
#define KP 1056          // padded K = 33*32 (bias column at 1024)
#define GNT 33           // KP/32

// ---------------- helpers ----------------
__device__ inline unsigned f2bf(float f) {
    unsigned u = __builtin_bit_cast(unsigned, f);
    u += 0x7fffu + ((u >> 16) & 1u);          // RNE
    return u >> 16;
}
__device__ inline float bf2f(unsigned u) {
    return __builtin_bit_cast(float, u << 16);
}
__device__ inline float sigf(float x) {
    return 1.0f / (1.0f + __expf(-x));
}
__device__ inline float tanh_fast(float x) {
    return __builtin_fmaf(2.0f, 1.0f / (1.0f + __expf(-2.0f * x)), -1.0f);
}
__device__ inline float wred(float v) {
#pragma unroll
    for (int o = 32; o > 0; o >>= 1) v += __shfl_xor(v, o);
    return v;
}
__device__ inline void gload_lds16(const void* g, void* l) {
    __builtin_amdgcn_global_load_lds(
        (const __attribute__((address_space(1))) void*)g,
        (__attribute__((address_space(3))) void*)l, 16, 0, 0);
}

// ---------------- cast f32 -> bf16 into K-augmented buffers ----------------
__global__ __launch_bounds__(256) void cast_aug(
    const float* __restrict__ inputs, const float* __restrict__ hx,
    const float* __restrict__ w_ih,   const float* __restrict__ w_hh,
    const float* __restrict__ b_hh,
    unsigned short* __restrict__ Abf, unsigned short* __restrict__ Hbf,
    unsigned short* __restrict__ Wih, unsigned short* __restrict__ Whh)
{
    const int CPR = 132;                       // 8-elem chunks per 1056-row
    const int PERREG = 4096 * CPR;
    int j = blockIdx.x * blockDim.x + threadIdx.x;
    const int r = j / PERREG;
    if (r >= 4) return;
    const int rem = j - r * PERREG;
    const int row = rem / CPR;
    const int c8  = rem - row * CPR;

    const float* src; unsigned short* dst;
    switch (r) {
        case 0: src = inputs; dst = Abf; break;
        case 1: src = hx;     dst = Hbf; break;
        case 2: src = w_ih;   dst = Wih; break;
        default: src = w_hh;  dst = Whh; break;
    }

    uint4 v;
    if (c8 < 128) {
        const float4* sp = reinterpret_cast<const float4*>(src + (size_t)row * 1024 + c8 * 8);
        float4 a = sp[0], b = sp[1];
        v.x = f2bf(a.x) | (f2bf(a.y) << 16);
        v.y = f2bf(a.z) | (f2bf(a.w) << 16);
        v.z = f2bf(b.x) | (f2bf(b.y) << 16);
        v.w = f2bf(b.z) | (f2bf(b.w) << 16);
    } else {
        v.x = v.y = v.z = v.w = 0u;
        if (c8 == 128) {
            if (r == 1) v.x = 0x3F80u;                    // bf16(1.0)
            else if (r == 3) v.x = f2bf(b_hh[row]);
        }
    }
    *reinterpret_cast<uint4*>(dst + (size_t)row * KP + c8 * 8) = v;
}

// =====================================================================
// 128(batch) x 256(gate) bf16 NT GEMM tile, K=1056 (bias-augmented).
// Ring-2 LDS (48 KiB), __launch_bounds__(512,6) -> 3 RESIDENT BLOCKS/CU
// (VGPR<=64, LDS 3x48K=144K<=160K): co-resident blocks fill per-tile
// vmcnt(0) stalls and hide prologue/epilogue. 8 waves = 2(batch) x
// 4(gate); wave tile 64x64; one barrier per K-tile. 16x16x32 MFMA,
// swapped operands: acc[f][n] = mfma(W[f], X[n]). Epilogue: raw-f32 LN
// stats -> P[row][64] partials; pack + uint2 C stores.
// =====================================================================
__global__ __launch_bounds__(512, 6) void gemmr2(
    const unsigned short* __restrict__ Aa, const unsigned short* __restrict__ Ba, unsigned short* __restrict__ Ca,
    const unsigned short* __restrict__ Ab, const unsigned short* __restrict__ Bb, unsigned short* __restrict__ Cb,
    float2* __restrict__ P,           // [2][Bn][64] per-row partials (bx*4+wg)
    int N, int Bn)
{
    __shared__ __attribute__((aligned(16))) short lds[24576];  // 48 KiB
    short* ldsW = lds;              // 2 slots x 8192 shorts (256 gates x 32 k)
    short* ldsX = lds + 16384;      // 2 slots x 4096 shorts (128 rows x 32 k)

    // ---- bijective XCD swizzle over 1024 blocks ----
    const int gx  = gridDim.x;            // 16
    const int gxy = gx * gridDim.y;       // 512
    int bid = (blockIdx.z * gridDim.y + blockIdx.y) * gx + blockIdx.x;
    const int cpx = (gxy * gridDim.z) >> 3;   // 128
    int swz = (bid & 7) * cpx + (bid >> 3);
    const int z  = swz / gxy;
    const int r2 = swz - z * gxy;
    const int by = r2 / gx;
    const int bx = r2 - by * gx;

    const unsigned short* __restrict__ X = z ? Ab : Aa;   // batch [Bn,KP]
    const unsigned short* __restrict__ W = z ? Bb : Ba;   // weights [N,KP]
    unsigned short* __restrict__ C = z ? Cb : Ca;
    const int brow = by * 128, bcol = bx * 256;

    const int t    = threadIdx.x;
    const int lane = t & 63, w = t >> 6;
    const int wg = w & 3, wb = w >> 2;    // wave: gate quadrant (64), batch half (64)
    const int lr = lane & 15, kc = lane >> 4;

    // ---- staging addresses: W 2 chunks/thread, X 1 chunk/thread ----
    const int ciW0 = t, ciW1 = t + 512;
    const int rW0 = ciW0 >> 2, lW0 = (ciW0 & 3) ^ ((rW0 >> 1) & 3);
    const int rW1 = ciW1 >> 2, lW1 = (ciW1 & 3) ^ ((rW1 >> 1) & 3);
    const int rX  = t >> 2,    lX  = (t & 3) ^ ((rX >> 1) & 3);
    const int gW0 = (bcol + rW0) * KP + lW0 * 8;
    const int gW1 = (bcol + rW1) * KP + lW1 * 8;
    const int gX  = (brow + rX) * KP + lX * 8;
    const int dW0 = ciW0 * 8, dW1 = ciW1 * 8, dX = t * 8;

#define STAGE(u) { const int sW_ = ((u) & 1) * 8192, sX_ = ((u) & 1) * 4096; \
    gload_lds16(W + gW0 + (u) * 32, ldsW + sW_ + dW0); \
    gload_lds16(W + gW1 + (u) * 32, ldsW + sW_ + dW1); \
    gload_lds16(X + gX  + (u) * 32, ldsX + sX_ + dX); }

    // ---- ds_read offsets (XOR chunk swizzle) ----
    int offW[4], offX[4];
#pragma unroll
    for (int f = 0; f < 4; ++f) {
        int r = wg * 64 + f * 16 + lr;
        offW[f] = r * 32 + ((kc ^ ((r >> 1) & 3)) * 8);
    }
#pragma unroll
    for (int n = 0; n < 4; ++n) {
        int r = wb * 64 + n * 16 + lr;
        offX[n] = r * 32 + ((kc ^ ((r >> 1) & 3)) * 8);
    }

    f32x4 acc[4][4];
#pragma unroll
    for (int i = 0; i < 4; ++i)
#pragma unroll
        for (int j = 0; j < 4; ++j)
            acc[i][j] = (f32x4){0.f, 0.f, 0.f, 0.f};

    // ---- prologue ----
    STAGE(0);
    asm volatile("s_waitcnt vmcnt(0)" ::: "memory");
    __builtin_amdgcn_s_barrier();

#pragma unroll 2
    for (int T = 0; T < GNT; ++T) {
        const int sW = (T & 1) * 8192, sX = (T & 1) * 4096;
        if (T + 1 < GNT) STAGE(T + 1);
        bf16x8 w0 = *(const bf16x8*)&ldsW[sW + offW[0]];
        bf16x8 w1 = *(const bf16x8*)&ldsW[sW + offW[1]];
        bf16x8 w2 = *(const bf16x8*)&ldsW[sW + offW[2]];
        bf16x8 w3 = *(const bf16x8*)&ldsW[sW + offW[3]];
        bf16x8 x0 = *(const bf16x8*)&ldsX[sX + offX[0]];
        bf16x8 x1 = *(const bf16x8*)&ldsX[sX + offX[1]];
        bf16x8 x2 = *(const bf16x8*)&ldsX[sX + offX[2]];
        bf16x8 x3 = *(const bf16x8*)&ldsX[sX + offX[3]];
        asm volatile("s_waitcnt lgkmcnt(0)" ::: "memory");
        __builtin_amdgcn_sched_barrier(0);
        __builtin_amdgcn_s_setprio(1);
        acc[0][0] = __builtin_amdgcn_mfma_f32_16x16x32_bf16(w0, x0, acc[0][0], 0, 0, 0);
        acc[0][1] = __builtin_amdgcn_mfma_f32_16x16x32_bf16(w0, x1, acc[0][1], 0, 0, 0);
        acc[0][2] = __builtin_amdgcn_mfma_f32_16x16x32_bf16(w0, x2, acc[0][2], 0, 0, 0);
        acc[0][3] = __builtin_amdgcn_mfma_f32_16x16x32_bf16(w0, x3, acc[0][3], 0, 0, 0);
        acc[1][0] = __builtin_amdgcn_mfma_f32_16x16x32_bf16(w1, x0, acc[1][0], 0, 0, 0);
        acc[1][1] = __builtin_amdgcn_mfma_f32_16x16x32_bf16(w1, x1, acc[1][1], 0, 0, 0);
        acc[1][2] = __builtin_amdgcn_mfma_f32_16x16x32_bf16(w1, x2, acc[1][2], 0, 0, 0);
        acc[1][3] = __builtin_amdgcn_mfma_f32_16x16x32_bf16(w1, x3, acc[1][3], 0, 0, 0);
        acc[2][0] = __builtin_amdgcn_mfma_f32_16x16x32_bf16(w2, x0, acc[2][0], 0, 0, 0);
        acc[2][1] = __builtin_amdgcn_mfma_f32_16x16x32_bf16(w2, x1, acc[2][1], 0, 0, 0);
        acc[2][2] = __builtin_amdgcn_mfma_f32_16x16x32_bf16(w2, x2, acc[2][2], 0, 0, 0);
        acc[2][3] = __builtin_amdgcn_mfma_f32_16x16x32_bf16(w2, x3, acc[2][3], 0, 0, 0);
        acc[3][0] = __builtin_amdgcn_mfma_f32_16x16x32_bf16(w3, x0, acc[3][0], 0, 0, 0);
        acc[3][1] = __builtin_amdgcn_mfma_f32_16x16x32_bf16(w3, x1, acc[3][1], 0, 0, 0);
        acc[3][2] = __builtin_amdgcn_mfma_f32_16x16x32_bf16(w3, x2, acc[3][2], 0, 0, 0);
        acc[3][3] = __builtin_amdgcn_mfma_f32_16x16x32_bf16(w3, x3, acc[3][3], 0, 0, 0);
        __builtin_amdgcn_s_setprio(0);
        if (T + 1 < GNT) { asm volatile("s_waitcnt vmcnt(0)" ::: "memory"); }
        __builtin_amdgcn_s_barrier();
    }

    // ---- epilogue: raw-f32 stats + pack + uint2 stores ----
    const int gate0 = bcol + wg * 64 + kc * 4;
    const int row0  = brow + wb * 64 + lr;

    float s[4] = {0.f, 0.f, 0.f, 0.f}, q[4] = {0.f, 0.f, 0.f, 0.f};
#pragma unroll
    for (int f = 0; f < 4; ++f) {
#pragma unroll
        for (int n = 0; n < 4; ++n) {
            float a0 = acc[f][n][0], a1 = acc[f][n][1];
            float a2 = acc[f][n][2], a3 = acc[f][n][3];
            s[n] += (a0 + a1) + (a2 + a3);
            q[n] += __builtin_fmaf(a0, a0, a1 * a1) + __builtin_fmaf(a2, a2, a3 * a3);
            unsigned u0 = f2bf(a0), u1 = f2bf(a1), u2 = f2bf(a2), u3 = f2bf(a3);
            uint2 pk; pk.x = u0 | (u1 << 16); pk.y = u2 | (u3 << 16);
            *reinterpret_cast<uint2*>(&C[(size_t)(row0 + n * 16) * N + gate0 + f * 16]) = pk;
        }
    }
#pragma unroll
    for (int n = 0; n < 4; ++n) {
        s[n] += __shfl_xor(s[n], 16); s[n] += __shfl_xor(s[n], 32);
        q[n] += __shfl_xor(q[n], 16); q[n] += __shfl_xor(q[n], 32);
    }
    if (kc == 0) {
#pragma unroll
        for (int n = 0; n < 4; ++n) {
            float2 pr; pr.x = s[n]; pr.y = q[n];
            P[(size_t)(z * Bn + row0 + n * 16) * 64 + bx * 4 + wg] = pr;
        }
    }
#undef STAGE
}

// ---------------- single-pass LN + LSTM (stats folded from P) ----------------
__global__ __launch_bounds__(256) void ln_lstm(
    const unsigned short* __restrict__ i2h,   // [B,4H] bf16
    const unsigned short* __restrict__ h2h,   // [B,4H] bf16 (bias included)
    const float* __restrict__ cx,
    const float2* __restrict__ P,             // [2][B][64] partial (sum,sumsq)
    const float* __restrict__ g_ih, const float* __restrict__ be_ih,
    const float* __restrict__ g_hh, const float* __restrict__ be_hh,
    const float* __restrict__ g_ho, const float* __restrict__ be_ho,
    float* __restrict__ hy, float* __restrict__ cy, int H, int B)
{
    const int b = blockIdx.x;
    const int t = threadIdx.x;
    const int lane = t & 63;
    const int wave = t >> 6;
    const int H4 = 4 * H;
    const int h0 = t * 4;

    const unsigned short* xi = i2h + (size_t)b * H4;
    const unsigned short* xh = h2h + (size_t)b * H4;

    __shared__ float red[4][2];
    __shared__ float st[4];   // mI, rI, mH, rH

    if (wave < 2) {           // wave 0: i2h, wave 1: h2h — full-wave fold of 64 partials
        float2 v = P[((size_t)wave * B + b) * 64 + lane];
        v.x += __shfl_xor(v.x, 1);  v.y += __shfl_xor(v.y, 1);
        v.x += __shfl_xor(v.x, 2);  v.y += __shfl_xor(v.y, 2);
        v.x += __shfl_xor(v.x, 4);  v.y += __shfl_xor(v.y, 4);
        v.x += __shfl_xor(v.x, 8);  v.y += __shfl_xor(v.y, 8);
        v.x += __shfl_xor(v.x, 16); v.y += __shfl_xor(v.y, 16);
        v.x += __shfl_xor(v.x, 32); v.y += __shfl_xor(v.y, 32);
        if (lane == 0) {
            const float inv4H = 1.0f / (float)H4;
            float m = v.x * inv4H;
            float r = rsqrtf(v.y * inv4H - m * m + LN_EPS);
            st[wave * 2]     = m;
            st[wave * 2 + 1] = r;
        }
    }
    __syncthreads();
    const float mI = st[0], rI = st[1], mH = st[2], rH = st[3];

    float gate[4][4];
#pragma unroll
    for (int q = 0; q < 4; ++q) {
        const int j = q * H + h0;
        ushort4 vi = *reinterpret_cast<const ushort4*>(&xi[j]);
        ushort4 vh = *reinterpret_cast<const ushort4*>(&xh[j]);
        float4 gi = *reinterpret_cast<const float4*>(&g_ih[j]);
        float4 bi = *reinterpret_cast<const float4*>(&be_ih[j]);
        float4 gh = *reinterpret_cast<const float4*>(&g_hh[j]);
        float4 bh = *reinterpret_cast<const float4*>(&be_hh[j]);
        gate[q][0] = (bf2f(vi.x) - mI) * rI * gi.x + bi.x + (bf2f(vh.x) - mH) * rH * gh.x + bh.x;
        gate[q][1] = (bf2f(vi.y) - mI) * rI * gi.y + bi.y + (bf2f(vh.y) - mH) * rH * gh.y + bh.y;
        gate[q][2] = (bf2f(vi.z) - mI) * rI * gi.z + bi.z + (bf2f(vh.z) - mH) * rH * gh.z + bh.z;
        gate[q][3] = (bf2f(vi.w) - mI) * rI * gi.w + bi.w + (bf2f(vh.w) - mH) * rH * gh.w + bh.w;
    }

    float4 cxv = *reinterpret_cast<const float4*>(&cx[(size_t)b * H + h0]);
    float cvals[4] = {cxv.x, cxv.y, cxv.z, cxv.w};
    float tv[4], ov[4];
    float s2 = 0.f, q2 = 0.f;
    float4 cyv;
#pragma unroll
    for (int k = 0; k < 4; ++k) {
        float c = sigf(gate[1][k]) * cvals[k] + sigf(gate[0][k]) * tanh_fast(gate[3][k]);
        ((float*)&cyv)[k] = c;
        float tc = tanh_fast(c);
        tv[k] = tc; ov[k] = sigf(gate[2][k]);
        s2 += tc; q2 += tc * tc;
    }
    *reinterpret_cast<float4*>(&cy[(size_t)b * H + h0]) = cyv;

    s2 = wred(s2); q2 = wred(q2);
    if (lane == 0) { red[wave][0] = s2; red[wave][1] = q2; }
    __syncthreads();
    float S2 = red[0][0] + red[1][0] + red[2][0] + red[3][0];
    float Q2 = red[0][1] + red[1][1] + red[2][1] + red[3][1];
    const float invH = 1.0f / (float)H;
    float mt = S2 * invH;
    float rt = rsqrtf(Q2 * invH - mt * mt + LN_EPS);

    float4 go = *reinterpret_cast<const float4*>(&g_ho[h0]);
    float4 bo = *reinterpret_cast<const float4*>(&be_ho[h0]);
    float4 hyv;
    hyv.x = ov[0] * ((tv[0] - mt) * rt * go.x + bo.x);
    hyv.y = ov[1] * ((tv[1] - mt) * rt * go.y + bo.y);
    hyv.z = ov[2] * ((tv[2] - mt) * rt * go.z + bo.z);
    hyv.w = ov[3] * ((tv[3] - mt) * rt * go.w + bo.w);
    *reinterpret_cast<float4*>(&hy[(size_t)b * H + h0]) = hyv;
}

// ---------------- launcher ----------------
extern "C" void kernel_launch(void* const* d_in, const int* in_sizes, int n_in,
                              void* d_out, int out_size, void* d_ws, size_t ws_size,
                              hipStream_t stream) {
    const float* inputs  = (const float*)d_in[0];
    const float* hx      = (const float*)d_in[1];
    const float* cx      = (const float*)d_in[2];
    const float* w_ih    = (const float*)d_in[3];
    const float* w_hh    = (const float*)d_in[4];
    const float* b_hh    = (const float*)d_in[5];
    const float* g_ih    = (const float*)d_in[6];
    const float* beta_ih = (const float*)d_in[7];
    const float* g_hh    = (const float*)d_in[8];
    const float* beta_hh = (const float*)d_in[9];
    const float* g_ho    = (const float*)d_in[10];
    const float* beta_ho = (const float*)d_in[11];

    const int H  = in_sizes[10];            // 1024
    const int B  = in_sizes[1] / H;         // 4096
    const int H4 = 4 * H;

    uint8_t* ws = (uint8_t*)d_ws;
    size_t off = 0;
    unsigned short* Abf = (unsigned short*)(ws + off); off += (size_t)B * KP * 2;
    unsigned short* Hbf = (unsigned short*)(ws + off); off += (size_t)B * KP * 2;
    unsigned short* Wih = (unsigned short*)(ws + off); off += (size_t)H4 * KP * 2;
    unsigned short* Whh = (unsigned short*)(ws + off); off += (size_t)H4 * KP * 2;
    unsigned short* i2hb = (unsigned short*)(ws + off); off += (size_t)B * H4 * 2;
    unsigned short* h2hb = (unsigned short*)(ws + off); off += (size_t)B * H4 * 2;
    float2* P   = (float2*)(ws + off); off += (size_t)2 * B * 64 * sizeof(float2);

    float* hy  = (float*)d_out;
    float* cyo = (float*)d_out + (size_t)B * H;

    // 1) casts into K-augmented buffers (bias baked into Hbf/Whh)
    {
        const int tot = 4 * 4096 * 132;
        cast_aug<<<(tot + 255) / 256, 256, 0, stream>>>(
            inputs, hx, w_ih, w_hh, b_hh, Abf, Hbf, Wih, Whh);
    }

    // 2) both GEMMs (K=1056), ring-2 LDS, 3 resident blocks/CU
    {
        dim3 grid(H4 / 256, B / 128, 2);    // 16 x 32 x 2 = 1024 blocks
        gemmr2<<<grid, 512, 0, stream>>>(Abf, Wih, i2hb, Hbf, Whh, h2hb, P, H4, B);
    }

    // 3) single-pass LN + LSTM (folds partials; h2h already biased)
    ln_lstm<<<B, 256, 0, stream>>>(i2hb, h2hb, cx, P,
                                   g_ih, beta_ih, g_hh, beta_hh, g_ho, beta_ho,
                                   hy, cyo, H, B);
}

// Round 14
// 161.447 us; speedup vs baseline: 5.1962x; 5.1962x over previous
//
#include <hip/hip_runtime.h>
#include <hip/hip_bf16.h>
#include <stdint.h>

typedef __attribute__((ext_vector_type(8))) short bf16x8;
typedef __attribute__((ext_vector_type(4))) float f32x4;

#define LN_EPS 1e-5f
#define KP 1056          // padded K = 33*32 (bias column at 1024)
#define GNT 33           // KP/32

// ---------------- helpers ----------------
__device__ inline unsigned f2bf(float f) {
    unsigned u = __builtin_bit_cast(unsigned, f);
    u += 0x7fffu + ((u >> 16) & 1u);          // RNE
    return u >> 16;
}
__device__ inline float bf2f(unsigned u) {
    return __builtin_bit_cast(float, u << 16);
}
__device__ inline float sigf(float x) {
    return 1.0f / (1.0f + __expf(-x));
}
__device__ inline float tanh_fast(float x) {
    return __builtin_fmaf(2.0f, 1.0f / (1.0f + __expf(-2.0f * x)), -1.0f);
}
__device__ inline float wred(float v) {
#pragma unroll
    for (int o = 32; o > 0; o >>= 1) v += __shfl_xor(v, o);
    return v;
}
__device__ inline void gload_lds16(const void* g, void* l) {
    __builtin_amdgcn_global_load_lds(
        (const __attribute__((address_space(1))) void*)g,
        (__attribute__((address_space(3))) void*)l, 16, 0, 0);
}

// ---------------- cast f32 -> bf16 into K-augmented buffers ----------------
__global__ __launch_bounds__(256) void cast_aug(
    const float* __restrict__ inputs, const float* __restrict__ hx,
    const float* __restrict__ w_ih,   const float* __restrict__ w_hh,
    const float* __restrict__ b_hh,
    unsigned short* __restrict__ Abf, unsigned short* __restrict__ Hbf,
    unsigned short* __restrict__ Wih, unsigned short* __restrict__ Whh)
{
    const int CPR = 132;                       // 8-elem chunks per 1056-row
    const int PERREG = 4096 * CPR;
    int j = blockIdx.x * blockDim.x + threadIdx.x;
    const int r = j / PERREG;
    if (r >= 4) return;
    const int rem = j - r * PERREG;
    const int row = rem / CPR;
    const int c8  = rem - row * CPR;

    const float* src; unsigned short* dst;
    switch (r) {
        case 0: src = inputs; dst = Abf; break;
        case 1: src = hx;     dst = Hbf; break;
        case 2: src = w_ih;   dst = Wih; break;
        default: src = w_hh;  dst = Whh; break;
    }

    uint4 v;
    if (c8 < 128) {
        const float4* sp = reinterpret_cast<const float4*>(src + (size_t)row * 1024 + c8 * 8);
        float4 a = sp[0], b = sp[1];
        v.x = f2bf(a.x) | (f2bf(a.y) << 16);
        v.y = f2bf(a.z) | (f2bf(a.w) << 16);
        v.z = f2bf(b.x) | (f2bf(b.y) << 16);
        v.w = f2bf(b.z) | (f2bf(b.w) << 16);
    } else {
        v.x = v.y = v.z = v.w = 0u;
        if (c8 == 128) {
            if (r == 1) v.x = 0x3F80u;                    // bf16(1.0)
            else if (r == 3) v.x = f2bf(b_hh[row]);
        }
    }
    *reinterpret_cast<uint4*>(dst + (size_t)row * KP + c8 * 8) = v;
}

// =====================================================================
// 128(batch) x 256(gate) bf16 NT GEMM tile, K=1056 (bias-augmented).
// RING-3 LDS (72 KiB) + COUNTED vmcnt(3): tile T+1's loads stay in
// flight across the per-tile barrier (T4); 2 resident blocks/CU
// (launch_bounds 512,4 — NOT 6: R13 showed 6 forces acc spill) hide
// the remaining stalls. 8 waves = 2(batch) x 4(gate); wave tile 64x64;
// one barrier per K-tile. 16x16x32 MFMA, swapped operands. Epilogue:
// raw-f32 LN stats -> P[row][64]; pack + uint2 C stores.
// Ring-3 ledger: slot (T+2)%3 last read by tile T-1, whose ds_reads all
// completed before barrier(T) (lgkmcnt(0) precedes each wave's barrier);
// vmcnt(3) at iter T => tile T's 3 loads done, T+1's outstanding.
// =====================================================================
__global__ __launch_bounds__(512, 4) void gemmr3(
    const unsigned short* __restrict__ Aa, const unsigned short* __restrict__ Ba, unsigned short* __restrict__ Ca,
    const unsigned short* __restrict__ Ab, const unsigned short* __restrict__ Bb, unsigned short* __restrict__ Cb,
    float2* __restrict__ P,           // [2][Bn][64] per-row partials (bx*4+wg)
    int N, int Bn)
{
    __shared__ __attribute__((aligned(16))) short lds[36864];  // 72 KiB
    short* ldsW = lds;              // 3 slots x 8192 shorts (256 gates x 32 k)
    short* ldsX = lds + 24576;      // 3 slots x 4096 shorts (128 rows x 32 k)

    // ---- bijective XCD swizzle over 1024 blocks ----
    const int gx  = gridDim.x;            // 16
    const int gxy = gx * gridDim.y;       // 512
    int bid = (blockIdx.z * gridDim.y + blockIdx.y) * gx + blockIdx.x;
    const int cpx = (gxy * gridDim.z) >> 3;   // 128
    int swz = (bid & 7) * cpx + (bid >> 3);
    const int z  = swz / gxy;
    const int r2 = swz - z * gxy;
    const int by = r2 / gx;
    const int bx = r2 - by * gx;

    const unsigned short* __restrict__ X = z ? Ab : Aa;   // batch [Bn,KP]
    const unsigned short* __restrict__ W = z ? Bb : Ba;   // weights [N,KP]
    unsigned short* __restrict__ C = z ? Cb : Ca;
    const int brow = by * 128, bcol = bx * 256;

    const int t    = threadIdx.x;
    const int lane = t & 63, w = t >> 6;
    const int wg = w & 3, wb = w >> 2;    // wave: gate quadrant (64), batch half (64)
    const int lr = lane & 15, kc = lane >> 4;

    // ---- staging addresses: W 2 chunks/thread, X 1 chunk/thread ----
    const int ciW0 = t, ciW1 = t + 512;
    const int rW0 = ciW0 >> 2, lW0 = (ciW0 & 3) ^ ((rW0 >> 1) & 3);
    const int rW1 = ciW1 >> 2, lW1 = (ciW1 & 3) ^ ((rW1 >> 1) & 3);
    const int rX  = t >> 2,    lX  = (t & 3) ^ ((rX >> 1) & 3);
    const int gW0 = (bcol + rW0) * KP + lW0 * 8;
    const int gW1 = (bcol + rW1) * KP + lW1 * 8;
    const int gX  = (brow + rX) * KP + lX * 8;
    const int dW0 = ciW0 * 8, dW1 = ciW1 * 8, dX = t * 8;

#define STAGE(u, slot) { const int sW_ = (slot) * 8192, sX_ = (slot) * 4096; \
    gload_lds16(W + gW0 + (u) * 32, ldsW + sW_ + dW0); \
    gload_lds16(W + gW1 + (u) * 32, ldsW + sW_ + dW1); \
    gload_lds16(X + gX  + (u) * 32, ldsX + sX_ + dX); }

    // ---- ds_read offsets (XOR chunk swizzle) ----
    int offW[4], offX[4];
#pragma unroll
    for (int f = 0; f < 4; ++f) {
        int r = wg * 64 + f * 16 + lr;
        offW[f] = r * 32 + ((kc ^ ((r >> 1) & 3)) * 8);
    }
#pragma unroll
    for (int n = 0; n < 4; ++n) {
        int r = wb * 64 + n * 16 + lr;
        offX[n] = r * 32 + ((kc ^ ((r >> 1) & 3)) * 8);
    }

    f32x4 acc[4][4];
#pragma unroll
    for (int i = 0; i < 4; ++i)
#pragma unroll
        for (int j = 0; j < 4; ++j)
            acc[i][j] = (f32x4){0.f, 0.f, 0.f, 0.f};

    // ---- prologue: stage tiles 0 and 1 ----
    STAGE(0, 0); STAGE(1, 1);

    int sCur = 0;          // slot of tile T
    int sNxt2 = 2;         // slot for tile T+2
#pragma unroll 3
    for (int T = 0; T < GNT; ++T) {
        if (T + 1 < GNT) { asm volatile("s_waitcnt vmcnt(3)" ::: "memory"); }
        else             { asm volatile("s_waitcnt vmcnt(0)" ::: "memory"); }
        __builtin_amdgcn_s_barrier();

        const int sW = sCur * 8192, sX = sCur * 4096;
        bf16x8 w0 = *(const bf16x8*)&ldsW[sW + offW[0]];
        bf16x8 w1 = *(const bf16x8*)&ldsW[sW + offW[1]];
        bf16x8 w2 = *(const bf16x8*)&ldsW[sW + offW[2]];
        bf16x8 w3 = *(const bf16x8*)&ldsW[sW + offW[3]];
        bf16x8 x0 = *(const bf16x8*)&ldsX[sX + offX[0]];
        bf16x8 x1 = *(const bf16x8*)&ldsX[sX + offX[1]];
        bf16x8 x2 = *(const bf16x8*)&ldsX[sX + offX[2]];
        bf16x8 x3 = *(const bf16x8*)&ldsX[sX + offX[3]];
        if (T + 2 < GNT) STAGE(T + 2, sNxt2);
        asm volatile("s_waitcnt lgkmcnt(0)" ::: "memory");
        __builtin_amdgcn_sched_barrier(0);
        __builtin_amdgcn_s_setprio(1);
        acc[0][0] = __builtin_amdgcn_mfma_f32_16x16x32_bf16(w0, x0, acc[0][0], 0, 0, 0);
        acc[0][1] = __builtin_amdgcn_mfma_f32_16x16x32_bf16(w0, x1, acc[0][1], 0, 0, 0);
        acc[0][2] = __builtin_amdgcn_mfma_f32_16x16x32_bf16(w0, x2, acc[0][2], 0, 0, 0);
        acc[0][3] = __builtin_amdgcn_mfma_f32_16x16x32_bf16(w0, x3, acc[0][3], 0, 0, 0);
        acc[1][0] = __builtin_amdgcn_mfma_f32_16x16x32_bf16(w1, x0, acc[1][0], 0, 0, 0);
        acc[1][1] = __builtin_amdgcn_mfma_f32_16x16x32_bf16(w1, x1, acc[1][1], 0, 0, 0);
        acc[1][2] = __builtin_amdgcn_mfma_f32_16x16x32_bf16(w1, x2, acc[1][2], 0, 0, 0);
        acc[1][3] = __builtin_amdgcn_mfma_f32_16x16x32_bf16(w1, x3, acc[1][3], 0, 0, 0);
        acc[2][0] = __builtin_amdgcn_mfma_f32_16x16x32_bf16(w2, x0, acc[2][0], 0, 0, 0);
        acc[2][1] = __builtin_amdgcn_mfma_f32_16x16x32_bf16(w2, x1, acc[2][1], 0, 0, 0);
        acc[2][2] = __builtin_amdgcn_mfma_f32_16x16x32_bf16(w2, x2, acc[2][2], 0, 0, 0);
        acc[2][3] = __builtin_amdgcn_mfma_f32_16x16x32_bf16(w2, x3, acc[2][3], 0, 0, 0);
        acc[3][0] = __builtin_amdgcn_mfma_f32_16x16x32_bf16(w3, x0, acc[3][0], 0, 0, 0);
        acc[3][1] = __builtin_amdgcn_mfma_f32_16x16x32_bf16(w3, x1, acc[3][1], 0, 0, 0);
        acc[3][2] = __builtin_amdgcn_mfma_f32_16x16x32_bf16(w3, x2, acc[3][2], 0, 0, 0);
        acc[3][3] = __builtin_amdgcn_mfma_f32_16x16x32_bf16(w3, x3, acc[3][3], 0, 0, 0);
        __builtin_amdgcn_s_setprio(0);

        sCur  = (sCur == 2)  ? 0 : sCur + 1;
        sNxt2 = (sNxt2 == 2) ? 0 : sNxt2 + 1;
    }

    // ---- epilogue: raw-f32 stats + pack + uint2 stores ----
    const int gate0 = bcol + wg * 64 + kc * 4;
    const int row0  = brow + wb * 64 + lr;

    float s[4] = {0.f, 0.f, 0.f, 0.f}, q[4] = {0.f, 0.f, 0.f, 0.f};
#pragma unroll
    for (int f = 0; f < 4; ++f) {
#pragma unroll
        for (int n = 0; n < 4; ++n) {
            float a0 = acc[f][n][0], a1 = acc[f][n][1];
            float a2 = acc[f][n][2], a3 = acc[f][n][3];
            s[n] += (a0 + a1) + (a2 + a3);
            q[n] += __builtin_fmaf(a0, a0, a1 * a1) + __builtin_fmaf(a2, a2, a3 * a3);
            unsigned u0 = f2bf(a0), u1 = f2bf(a1), u2 = f2bf(a2), u3 = f2bf(a3);
            uint2 pk; pk.x = u0 | (u1 << 16); pk.y = u2 | (u3 << 16);
            *reinterpret_cast<uint2*>(&C[(size_t)(row0 + n * 16) * N + gate0 + f * 16]) = pk;
        }
    }
#pragma unroll
    for (int n = 0; n < 4; ++n) {
        s[n] += __shfl_xor(s[n], 16); s[n] += __shfl_xor(s[n], 32);
        q[n] += __shfl_xor(q[n], 16); q[n] += __shfl_xor(q[n], 32);
    }
    if (kc == 0) {
#pragma unroll
        for (int n = 0; n < 4; ++n) {
            float2 pr; pr.x = s[n]; pr.y = q[n];
            P[(size_t)(z * Bn + row0 + n * 16) * 64 + bx * 4 + wg] = pr;
        }
    }
#undef STAGE
}

// ---------------- single-pass LN + LSTM (stats folded from P) ----------------
__global__ __launch_bounds__(256) void ln_lstm(
    const unsigned short* __restrict__ i2h,   // [B,4H] bf16
    const unsigned short* __restrict__ h2h,   // [B,4H] bf16 (bias included)
    const float* __restrict__ cx,
    const float2* __restrict__ P,             // [2][B][64] partial (sum,sumsq)
    const float* __restrict__ g_ih, const float* __restrict__ be_ih,
    const float* __restrict__ g_hh, const float* __restrict__ be_hh,
    const float* __restrict__ g_ho, const float* __restrict__ be_ho,
    float* __restrict__ hy, float* __restrict__ cy, int H, int B)
{
    const int b = blockIdx.x;
    const int t = threadIdx.x;
    const int lane = t & 63;
    const int wave = t >> 6;
    const int H4 = 4 * H;
    const int h0 = t * 4;

    const unsigned short* xi = i2h + (size_t)b * H4;
    const unsigned short* xh = h2h + (size_t)b * H4;

    __shared__ float red[4][2];
    __shared__ float st[4];   // mI, rI, mH, rH

    if (wave < 2) {           // wave 0: i2h, wave 1: h2h — full-wave fold of 64 partials
        float2 v = P[((size_t)wave * B + b) * 64 + lane];
        v.x += __shfl_xor(v.x, 1);  v.y += __shfl_xor(v.y, 1);
        v.x += __shfl_xor(v.x, 2);  v.y += __shfl_xor(v.y, 2);
        v.x += __shfl_xor(v.x, 4);  v.y += __shfl_xor(v.y, 4);
        v.x += __shfl_xor(v.x, 8);  v.y += __shfl_xor(v.y, 8);
        v.x += __shfl_xor(v.x, 16); v.y += __shfl_xor(v.y, 16);
        v.x += __shfl_xor(v.x, 32); v.y += __shfl_xor(v.y, 32);
        if (lane == 0) {
            const float inv4H = 1.0f / (float)H4;
            float m = v.x * inv4H;
            float r = rsqrtf(v.y * inv4H - m * m + LN_EPS);
            st[wave * 2]     = m;
            st[wave * 2 + 1] = r;
        }
    }
    __syncthreads();
    const float mI = st[0], rI = st[1], mH = st[2], rH = st[3];

    float gate[4][4];
#pragma unroll
    for (int q = 0; q < 4; ++q) {
        const int j = q * H + h0;
        ushort4 vi = *reinterpret_cast<const ushort4*>(&xi[j]);
        ushort4 vh = *reinterpret_cast<const ushort4*>(&xh[j]);
        float4 gi = *reinterpret_cast<const float4*>(&g_ih[j]);
        float4 bi = *reinterpret_cast<const float4*>(&be_ih[j]);
        float4 gh = *reinterpret_cast<const float4*>(&g_hh[j]);
        float4 bh = *reinterpret_cast<const float4*>(&be_hh[j]);
        gate[q][0] = (bf2f(vi.x) - mI) * rI * gi.x + bi.x + (bf2f(vh.x) - mH) * rH * gh.x + bh.x;
        gate[q][1] = (bf2f(vi.y) - mI) * rI * gi.y + bi.y + (bf2f(vh.y) - mH) * rH * gh.y + bh.y;
        gate[q][2] = (bf2f(vi.z) - mI) * rI * gi.z + bi.z + (bf2f(vh.z) - mH) * rH * gh.z + bh.z;
        gate[q][3] = (bf2f(vi.w) - mI) * rI * gi.w + bi.w + (bf2f(vh.w) - mH) * rH * gh.w + bh.w;
    }

    float4 cxv = *reinterpret_cast<const float4*>(&cx[(size_t)b * H + h0]);
    float cvals[4] = {cxv.x, cxv.y, cxv.z, cxv.w};
    float tv[4], ov[4];
    float s2 = 0.f, q2 = 0.f;
    float4 cyv;
#pragma unroll
    for (int k = 0; k < 4; ++k) {
        float c = sigf(gate[1][k]) * cvals[k] + sigf(gate[0][k]) * tanh_fast(gate[3][k]);
        ((float*)&cyv)[k] = c;
        float tc = tanh_fast(c);
        tv[k] = tc; ov[k] = sigf(gate[2][k]);
        s2 += tc; q2 += tc * tc;
    }
    *reinterpret_cast<float4*>(&cy[(size_t)b * H + h0]) = cyv;

    s2 = wred(s2); q2 = wred(q2);
    if (lane == 0) { red[wave][0] = s2; red[wave][1] = q2; }
    __syncthreads();
    float S2 = red[0][0] + red[1][0] + red[2][0] + red[3][0];
    float Q2 = red[0][1] + red[1][1] + red[2][1] + red[3][1];
    const float invH = 1.0f / (float)H;
    float mt = S2 * invH;
    float rt = rsqrtf(Q2 * invH - mt * mt + LN_EPS);

    float4 go = *reinterpret_cast<const float4*>(&g_ho[h0]);
    float4 bo = *reinterpret_cast<const float4*>(&be_ho[h0]);
    float4 hyv;
    hyv.x = ov[0] * ((tv[0] - mt) * rt * go.x + bo.x);
    hyv.y = ov[1] * ((tv[1] - mt) * rt * go.y + bo.y);
    hyv.z = ov[2] * ((tv[2] - mt) * rt * go.z + bo.z);
    hyv.w = ov[3] * ((tv[3] - mt) * rt * go.w + bo.w);
    *reinterpret_cast<float4*>(&hy[(size_t)b * H + h0]) = hyv;
}

// ---------------- launcher ----------------
extern "C" void kernel_launch(void* const* d_in, const int* in_sizes, int n_in,
                              void* d_out, int out_size, void* d_ws, size_t ws_size,
                              hipStream_t stream) {
    const float* inputs  = (const float*)d_in[0];
    const float* hx      = (const float*)d_in[1];
    const float* cx      = (const float*)d_in[2];
    const float* w_ih    = (const float*)d_in[3];
    const float* w_hh    = (const float*)d_in[4];
    const float* b_hh    = (const float*)d_in[5];
    const float* g_ih    = (const float*)d_in[6];
    const float* beta_ih = (const float*)d_in[7];
    const float* g_hh    = (const float*)d_in[8];
    const float* beta_hh = (const float*)d_in[9];
    const float* g_ho    = (const float*)d_in[10];
    const float* beta_ho = (const float*)d_in[11];

    const int H  = in_sizes[10];            // 1024
    const int B  = in_sizes[1] / H;         // 4096
    const int H4 = 4 * H;

    uint8_t* ws = (uint8_t*)d_ws;
    size_t off = 0;
    unsigned short* Abf = (unsigned short*)(ws + off); off += (size_t)B * KP * 2;
    unsigned short* Hbf = (unsigned short*)(ws + off); off += (size_t)B * KP * 2;
    unsigned short* Wih = (unsigned short*)(ws + off); off += (size_t)H4 * KP * 2;
    unsigned short* Whh = (unsigned short*)(ws + off); off += (size_t)H4 * KP * 2;
    unsigned short* i2hb = (unsigned short*)(ws + off); off += (size_t)B * H4 * 2;
    unsigned short* h2hb = (unsigned short*)(ws + off); off += (size_t)B * H4 * 2;
    float2* P   = (float2*)(ws + off); off += (size_t)2 * B * 64 * sizeof(float2);

    float* hy  = (float*)d_out;
    float* cyo = (float*)d_out + (size_t)B * H;

    // 1) casts into K-augmented buffers (bias baked into Hbf/Whh)
    {
        const int tot = 4 * 4096 * 132;
        cast_aug<<<(tot + 255) / 256, 256, 0, stream>>>(
            inputs, hx, w_ih, w_hh, b_hh, Abf, Hbf, Wih, Whh);
    }

    // 2) both GEMMs (K=1056), ring-3 LDS, counted vmcnt, 2 resident blocks/CU
    {
        dim3 grid(H4 / 256, B / 128, 2);    // 16 x 32 x 2 = 1024 blocks
        gemmr3<<<grid, 512, 0, stream>>>(Abf, Wih, i2hb, Hbf, Whh, h2hb, P, H4, B);
    }

    // 3) single-pass LN + LSTM (folds partials; h2h already biased)
    ln_lstm<<<B, 256, 0, stream>>>(i2hb, h2hb, cx, P,
                                   g_ih, beta_ih, g_hh, beta_hh, g_ho, beta_ho,
                                   hy, cyo, H, B);
}

// Round 15
// 130.662 us; speedup vs baseline: 6.4204x; 1.2356x over previous
//
#include <hip/hip_runtime.h>
#include <hip/hip_bf16.h>
#include <stdint.h>

typedef __attribute__((ext_vector_type(8))) short bf16x8;
typedef __attribute__((ext_vector_type(4))) float f32x4;

#define LN_EPS 1e-5f
#define KP 1056          // padded K = 33*32 (bias column at 1024)
#define GNT 33           // KP/32

// ---------------- helpers ----------------
__device__ inline unsigned f2bf(float f) {
    unsigned u = __builtin_bit_cast(unsigned, f);
    u += 0x7fffu + ((u >> 16) & 1u);          // RNE
    return u >> 16;
}
__device__ inline float bf2f(unsigned u) {
    return __builtin_bit_cast(float, u << 16);
}
__device__ inline float sigf(float x) {
    return 1.0f / (1.0f + __expf(-x));
}
__device__ inline float tanh_fast(float x) {
    return __builtin_fmaf(2.0f, 1.0f / (1.0f + __expf(-2.0f * x)), -1.0f);
}
__device__ inline void gload_lds16(const void* g, void* l) {
    __builtin_amdgcn_global_load_lds(
        (const __attribute__((address_space(1))) void*)g,
        (__attribute__((address_space(3))) void*)l, 16, 0, 0);
}

// ---------------- cast f32 -> bf16 into K-augmented buffers ----------------
__global__ __launch_bounds__(256) void cast_aug(
    const float* __restrict__ inputs, const float* __restrict__ hx,
    const float* __restrict__ w_ih,   const float* __restrict__ w_hh,
    const float* __restrict__ b_hh,
    unsigned short* __restrict__ Abf, unsigned short* __restrict__ Hbf,
    unsigned short* __restrict__ Wih, unsigned short* __restrict__ Whh)
{
    const int CPR = 132;                       // 8-elem chunks per 1056-row
    const int PERREG = 4096 * CPR;
    int j = blockIdx.x * blockDim.x + threadIdx.x;
    const int r = j / PERREG;
    if (r >= 4) return;
    const int rem = j - r * PERREG;
    const int row = rem / CPR;
    const int c8  = rem - row * CPR;

    const float* src; unsigned short* dst;
    switch (r) {
        case 0: src = inputs; dst = Abf; break;
        case 1: src = hx;     dst = Hbf; break;
        case 2: src = w_ih;   dst = Wih; break;
        default: src = w_hh;  dst = Whh; break;
    }

    uint4 v;
    if (c8 < 128) {
        const float4* sp = reinterpret_cast<const float4*>(src + (size_t)row * 1024 + c8 * 8);
        float4 a = sp[0], b = sp[1];
        v.x = f2bf(a.x) | (f2bf(a.y) << 16);
        v.y = f2bf(a.z) | (f2bf(a.w) << 16);
        v.z = f2bf(b.x) | (f2bf(b.y) << 16);
        v.w = f2bf(b.z) | (f2bf(b.w) << 16);
    } else {
        v.x = v.y = v.z = v.w = 0u;
        if (c8 == 128) {
            if (r == 1) v.x = 0x3F80u;                    // bf16(1.0)
            else if (r == 3) v.x = f2bf(b_hh[row]);
        }
    }
    *reinterpret_cast<uint4*>(dst + (size_t)row * KP + c8 * 8) = v;
}

// =====================================================================
// 128(batch) x 256(gate) bf16 NT GEMM tile, K=1056 (bias-augmented).
// R12 configuration EXACT (best measured GEMM dispatch: 96.0 us, 738 TF
// incl. stats): ring-2 LDS (48 KiB), __launch_bounds__(512,4) -> 2
// resident blocks/CU, one barrier + vmcnt(0) per K-tile, 16x16x32 MFMA,
// swapped operands acc[f][n] = mfma(W[f], X[n]), XOR chunk swizzle,
// bijective XCD swizzle. Epilogue: raw-f32 LN stats -> P[row][64];
// pack + uint2 C stores.
// =====================================================================
__global__ __launch_bounds__(512, 4) void gemmr2(
    const unsigned short* __restrict__ Aa, const unsigned short* __restrict__ Ba, unsigned short* __restrict__ Ca,
    const unsigned short* __restrict__ Ab, const unsigned short* __restrict__ Bb, unsigned short* __restrict__ Cb,
    float2* __restrict__ P,           // [2][Bn][64] per-row partials (bx*4+wg)
    int N, int Bn)
{
    __shared__ __attribute__((aligned(16))) short lds[24576];  // 48 KiB
    short* ldsW = lds;              // 2 slots x 8192 shorts (256 gates x 32 k)
    short* ldsX = lds + 16384;      // 2 slots x 4096 shorts (128 rows x 32 k)

    // ---- bijective XCD swizzle over 1024 blocks ----
    const int gx  = gridDim.x;            // 16
    const int gxy = gx * gridDim.y;       // 512
    int bid = (blockIdx.z * gridDim.y + blockIdx.y) * gx + blockIdx.x;
    const int cpx = (gxy * gridDim.z) >> 3;   // 128
    int swz = (bid & 7) * cpx + (bid >> 3);
    const int z  = swz / gxy;
    const int r2 = swz - z * gxy;
    const int by = r2 / gx;
    const int bx = r2 - by * gx;

    const unsigned short* __restrict__ X = z ? Ab : Aa;   // batch [Bn,KP]
    const unsigned short* __restrict__ W = z ? Bb : Ba;   // weights [N,KP]
    unsigned short* __restrict__ C = z ? Cb : Ca;
    const int brow = by * 128, bcol = bx * 256;

    const int t    = threadIdx.x;
    const int lane = t & 63, w = t >> 6;
    const int wg = w & 3, wb = w >> 2;    // wave: gate quadrant (64), batch half (64)
    const int lr = lane & 15, kc = lane >> 4;

    // ---- staging addresses: W 2 chunks/thread, X 1 chunk/thread ----
    const int ciW0 = t, ciW1 = t + 512;
    const int rW0 = ciW0 >> 2, lW0 = (ciW0 & 3) ^ ((rW0 >> 1) & 3);
    const int rW1 = ciW1 >> 2, lW1 = (ciW1 & 3) ^ ((rW1 >> 1) & 3);
    const int rX  = t >> 2,    lX  = (t & 3) ^ ((rX >> 1) & 3);
    const int gW0 = (bcol + rW0) * KP + lW0 * 8;
    const int gW1 = (bcol + rW1) * KP + lW1 * 8;
    const int gX  = (brow + rX) * KP + lX * 8;
    const int dW0 = ciW0 * 8, dW1 = ciW1 * 8, dX = t * 8;

#define STAGE(u) { const int sW_ = ((u) & 1) * 8192, sX_ = ((u) & 1) * 4096; \
    gload_lds16(W + gW0 + (u) * 32, ldsW + sW_ + dW0); \
    gload_lds16(W + gW1 + (u) * 32, ldsW + sW_ + dW1); \
    gload_lds16(X + gX  + (u) * 32, ldsX + sX_ + dX); }

    // ---- ds_read offsets (XOR chunk swizzle) ----
    int offW[4], offX[4];
#pragma unroll
    for (int f = 0; f < 4; ++f) {
        int r = wg * 64 + f * 16 + lr;
        offW[f] = r * 32 + ((kc ^ ((r >> 1) & 3)) * 8);
    }
#pragma unroll
    for (int n = 0; n < 4; ++n) {
        int r = wb * 64 + n * 16 + lr;
        offX[n] = r * 32 + ((kc ^ ((r >> 1) & 3)) * 8);
    }

    f32x4 acc[4][4];
#pragma unroll
    for (int i = 0; i < 4; ++i)
#pragma unroll
        for (int j = 0; j < 4; ++j)
            acc[i][j] = (f32x4){0.f, 0.f, 0.f, 0.f};

    // ---- prologue ----
    STAGE(0);
    asm volatile("s_waitcnt vmcnt(0)" ::: "memory");
    __builtin_amdgcn_s_barrier();

#pragma unroll 2
    for (int T = 0; T < GNT; ++T) {
        const int sW = (T & 1) * 8192, sX = (T & 1) * 4096;
        if (T + 1 < GNT) STAGE(T + 1);
        bf16x8 w0 = *(const bf16x8*)&ldsW[sW + offW[0]];
        bf16x8 w1 = *(const bf16x8*)&ldsW[sW + offW[1]];
        bf16x8 w2 = *(const bf16x8*)&ldsW[sW + offW[2]];
        bf16x8 w3 = *(const bf16x8*)&ldsW[sW + offW[3]];
        bf16x8 x0 = *(const bf16x8*)&ldsX[sX + offX[0]];
        bf16x8 x1 = *(const bf16x8*)&ldsX[sX + offX[1]];
        bf16x8 x2 = *(const bf16x8*)&ldsX[sX + offX[2]];
        bf16x8 x3 = *(const bf16x8*)&ldsX[sX + offX[3]];
        asm volatile("s_waitcnt lgkmcnt(0)" ::: "memory");
        __builtin_amdgcn_sched_barrier(0);
        __builtin_amdgcn_s_setprio(1);
        acc[0][0] = __builtin_amdgcn_mfma_f32_16x16x32_bf16(w0, x0, acc[0][0], 0, 0, 0);
        acc[0][1] = __builtin_amdgcn_mfma_f32_16x16x32_bf16(w0, x1, acc[0][1], 0, 0, 0);
        acc[0][2] = __builtin_amdgcn_mfma_f32_16x16x32_bf16(w0, x2, acc[0][2], 0, 0, 0);
        acc[0][3] = __builtin_amdgcn_mfma_f32_16x16x32_bf16(w0, x3, acc[0][3], 0, 0, 0);
        acc[1][0] = __builtin_amdgcn_mfma_f32_16x16x32_bf16(w1, x0, acc[1][0], 0, 0, 0);
        acc[1][1] = __builtin_amdgcn_mfma_f32_16x16x32_bf16(w1, x1, acc[1][1], 0, 0, 0);
        acc[1][2] = __builtin_amdgcn_mfma_f32_16x16x32_bf16(w1, x2, acc[1][2], 0, 0, 0);
        acc[1][3] = __builtin_amdgcn_mfma_f32_16x16x32_bf16(w1, x3, acc[1][3], 0, 0, 0);
        acc[2][0] = __builtin_amdgcn_mfma_f32_16x16x32_bf16(w2, x0, acc[2][0], 0, 0, 0);
        acc[2][1] = __builtin_amdgcn_mfma_f32_16x16x32_bf16(w2, x1, acc[2][1], 0, 0, 0);
        acc[2][2] = __builtin_amdgcn_mfma_f32_16x16x32_bf16(w2, x2, acc[2][2], 0, 0, 0);
        acc[2][3] = __builtin_amdgcn_mfma_f32_16x16x32_bf16(w2, x3, acc[2][3], 0, 0, 0);
        acc[3][0] = __builtin_amdgcn_mfma_f32_16x16x32_bf16(w3, x0, acc[3][0], 0, 0, 0);
        acc[3][1] = __builtin_amdgcn_mfma_f32_16x16x32_bf16(w3, x1, acc[3][1], 0, 0, 0);
        acc[3][2] = __builtin_amdgcn_mfma_f32_16x16x32_bf16(w3, x2, acc[3][2], 0, 0, 0);
        acc[3][3] = __builtin_amdgcn_mfma_f32_16x16x32_bf16(w3, x3, acc[3][3], 0, 0, 0);
        __builtin_amdgcn_s_setprio(0);
        if (T + 1 < GNT) { asm volatile("s_waitcnt vmcnt(0)" ::: "memory"); }
        __builtin_amdgcn_s_barrier();
    }

    // ---- epilogue: raw-f32 stats + pack + uint2 stores ----
    const int gate0 = bcol + wg * 64 + kc * 4;
    const int row0  = brow + wb * 64 + lr;

    float s[4] = {0.f, 0.f, 0.f, 0.f}, q[4] = {0.f, 0.f, 0.f, 0.f};
#pragma unroll
    for (int f = 0; f < 4; ++f) {
#pragma unroll
        for (int n = 0; n < 4; ++n) {
            float a0 = acc[f][n][0], a1 = acc[f][n][1];
            float a2 = acc[f][n][2], a3 = acc[f][n][3];
            s[n] += (a0 + a1) + (a2 + a3);
            q[n] += __builtin_fmaf(a0, a0, a1 * a1) + __builtin_fmaf(a2, a2, a3 * a3);
            unsigned u0 = f2bf(a0), u1 = f2bf(a1), u2 = f2bf(a2), u3 = f2bf(a3);
            uint2 pk; pk.x = u0 | (u1 << 16); pk.y = u2 | (u3 << 16);
            *reinterpret_cast<uint2*>(&C[(size_t)(row0 + n * 16) * N + gate0 + f * 16]) = pk;
        }
    }
#pragma unroll
    for (int n = 0; n < 4; ++n) {
        s[n] += __shfl_xor(s[n], 16); s[n] += __shfl_xor(s[n], 32);
        q[n] += __shfl_xor(q[n], 16); q[n] += __shfl_xor(q[n], 32);
    }
    if (kc == 0) {
#pragma unroll
        for (int n = 0; n < 4; ++n) {
            float2 pr; pr.x = s[n]; pr.y = q[n];
            P[(size_t)(z * Bn + row0 + n * 16) * 64 + bx * 4 + wg] = pr;
        }
    }
#undef STAGE
}

// ---------------- single-pass LN + LSTM (stats folded from P) ----------------
// Gate bf16 loads + cx issued BEFORE the P-fold so fold latency hides.
__global__ __launch_bounds__(256) void ln_lstm(
    const unsigned short* __restrict__ i2h,   // [B,4H] bf16
    const unsigned short* __restrict__ h2h,   // [B,4H] bf16 (bias included)
    const float* __restrict__ cx,
    const float2* __restrict__ P,             // [2][B][64] partial (sum,sumsq)
    const float* __restrict__ g_ih, const float* __restrict__ be_ih,
    const float* __restrict__ g_hh, const float* __restrict__ be_hh,
    const float* __restrict__ g_ho, const float* __restrict__ be_ho,
    float* __restrict__ hy, float* __restrict__ cy, int H, int B)
{
    const int b = blockIdx.x;
    const int t = threadIdx.x;
    const int lane = t & 63;
    const int wave = t >> 6;
    const int H4 = 4 * H;
    const int h0 = t * 4;

    const unsigned short* xi = i2h + (size_t)b * H4;
    const unsigned short* xh = h2h + (size_t)b * H4;

    __shared__ float red[4][2];
    __shared__ float st[4];   // mI, rI, mH, rH

    // ---- issue gate loads + cx early (independent of stats) ----
    ushort4 vi[4], vh[4];
#pragma unroll
    for (int q = 0; q < 4; ++q) {
        const int j = q * H + h0;
        vi[q] = *reinterpret_cast<const ushort4*>(&xi[j]);
        vh[q] = *reinterpret_cast<const ushort4*>(&xh[j]);
    }
    float4 cxv = *reinterpret_cast<const float4*>(&cx[(size_t)b * H + h0]);

    // ---- fold the 64 col-block partials (wave 0: i2h, wave 1: h2h) ----
    if (wave < 2) {
        float2 v = P[((size_t)wave * B + b) * 64 + lane];
        v.x += __shfl_xor(v.x, 1);  v.y += __shfl_xor(v.y, 1);
        v.x += __shfl_xor(v.x, 2);  v.y += __shfl_xor(v.y, 2);
        v.x += __shfl_xor(v.x, 4);  v.y += __shfl_xor(v.y, 4);
        v.x += __shfl_xor(v.x, 8);  v.y += __shfl_xor(v.y, 8);
        v.x += __shfl_xor(v.x, 16); v.y += __shfl_xor(v.y, 16);
        v.x += __shfl_xor(v.x, 32); v.y += __shfl_xor(v.y, 32);
        if (lane == 0) {
            const float inv4H = 1.0f / (float)H4;
            float m = v.x * inv4H;
            float r = rsqrtf(v.y * inv4H - m * m + LN_EPS);
            st[wave * 2]     = m;
            st[wave * 2 + 1] = r;
        }
    }
    __syncthreads();
    const float mI = st[0], rI = st[1], mH = st[2], rH = st[3];

    float gate[4][4];
#pragma unroll
    for (int q = 0; q < 4; ++q) {
        const int j = q * H + h0;
        float4 gi = *reinterpret_cast<const float4*>(&g_ih[j]);
        float4 bi = *reinterpret_cast<const float4*>(&be_ih[j]);
        float4 gh = *reinterpret_cast<const float4*>(&g_hh[j]);
        float4 bh = *reinterpret_cast<const float4*>(&be_hh[j]);
        gate[q][0] = (bf2f(vi[q].x) - mI) * rI * gi.x + bi.x + (bf2f(vh[q].x) - mH) * rH * gh.x + bh.x;
        gate[q][1] = (bf2f(vi[q].y) - mI) * rI * gi.y + bi.y + (bf2f(vh[q].y) - mH) * rH * gh.y + bh.y;
        gate[q][2] = (bf2f(vi[q].z) - mI) * rI * gi.z + bi.z + (bf2f(vh[q].z) - mH) * rH * gh.z + bh.z;
        gate[q][3] = (bf2f(vi[q].w) - mI) * rI * gi.w + bi.w + (bf2f(vh[q].w) - mH) * rH * gh.w + bh.w;
    }

    float cvals[4] = {cxv.x, cxv.y, cxv.z, cxv.w};
    float tv[4], ov[4];
    float s2 = 0.f, q2 = 0.f;
    float4 cyv;
#pragma unroll
    for (int k = 0; k < 4; ++k) {
        float c = sigf(gate[1][k]) * cvals[k] + sigf(gate[0][k]) * tanh_fast(gate[3][k]);
        ((float*)&cyv)[k] = c;
        float tc = tanh_fast(c);
        tv[k] = tc; ov[k] = sigf(gate[2][k]);
        s2 += tc; q2 += tc * tc;
    }
    *reinterpret_cast<float4*>(&cy[(size_t)b * H + h0]) = cyv;

#pragma unroll
    for (int o = 32; o > 0; o >>= 1) { s2 += __shfl_xor(s2, o); q2 += __shfl_xor(q2, o); }
    if (lane == 0) { red[wave][0] = s2; red[wave][1] = q2; }
    __syncthreads();
    float S2 = red[0][0] + red[1][0] + red[2][0] + red[3][0];
    float Q2 = red[0][1] + red[1][1] + red[2][1] + red[3][1];
    const float invH = 1.0f / (float)H;
    float mt = S2 * invH;
    float rt = rsqrtf(Q2 * invH - mt * mt + LN_EPS);

    float4 go = *reinterpret_cast<const float4*>(&g_ho[h0]);
    float4 bo = *reinterpret_cast<const float4*>(&be_ho[h0]);
    float4 hyv;
    hyv.x = ov[0] * ((tv[0] - mt) * rt * go.x + bo.x);
    hyv.y = ov[1] * ((tv[1] - mt) * rt * go.y + bo.y);
    hyv.z = ov[2] * ((tv[2] - mt) * rt * go.z + bo.z);
    hyv.w = ov[3] * ((tv[3] - mt) * rt * go.w + bo.w);
    *reinterpret_cast<float4*>(&hy[(size_t)b * H + h0]) = hyv;
}

// ---------------- launcher ----------------
extern "C" void kernel_launch(void* const* d_in, const int* in_sizes, int n_in,
                              void* d_out, int out_size, void* d_ws, size_t ws_size,
                              hipStream_t stream) {
    const float* inputs  = (const float*)d_in[0];
    const float* hx      = (const float*)d_in[1];
    const float* cx      = (const float*)d_in[2];
    const float* w_ih    = (const float*)d_in[3];
    const float* w_hh    = (const float*)d_in[4];
    const float* b_hh    = (const float*)d_in[5];
    const float* g_ih    = (const float*)d_in[6];
    const float* beta_ih = (const float*)d_in[7];
    const float* g_hh    = (const float*)d_in[8];
    const float* beta_hh = (const float*)d_in[9];
    const float* g_ho    = (const float*)d_in[10];
    const float* beta_ho = (const float*)d_in[11];

    const int H  = in_sizes[10];            // 1024
    const int B  = in_sizes[1] / H;         // 4096
    const int H4 = 4 * H;

    uint8_t* ws = (uint8_t*)d_ws;
    size_t off = 0;
    unsigned short* Abf = (unsigned short*)(ws + off); off += (size_t)B * KP * 2;
    unsigned short* Hbf = (unsigned short*)(ws + off); off += (size_t)B * KP * 2;
    unsigned short* Wih = (unsigned short*)(ws + off); off += (size_t)H4 * KP * 2;
    unsigned short* Whh = (unsigned short*)(ws + off); off += (size_t)H4 * KP * 2;
    unsigned short* i2hb = (unsigned short*)(ws + off); off += (size_t)B * H4 * 2;
    unsigned short* h2hb = (unsigned short*)(ws + off); off += (size_t)B * H4 * 2;
    float2* P   = (float2*)(ws + off); off += (size_t)2 * B * 64 * sizeof(float2);

    float* hy  = (float*)d_out;
    float* cyo = (float*)d_out + (size_t)B * H;

    // 1) casts into K-augmented buffers (bias baked into Hbf/Whh)
    {
        const int tot = 4 * 4096 * 132;
        cast_aug<<<(tot + 255) / 256, 256, 0, stream>>>(
            inputs, hx, w_ih, w_hh, b_hh, Abf, Hbf, Wih, Whh);
    }

    // 2) both GEMMs (K=1056), ring-2 LDS, 2 resident blocks/CU (R12 config)
    {
        dim3 grid(H4 / 256, B / 128, 2);    // 16 x 32 x 2 = 1024 blocks
        gemmr2<<<grid, 512, 0, stream>>>(Abf, Wih, i2hb, Hbf, Whh, h2hb, P, H4, B);
    }

    // 3) single-pass LN + LSTM (folds partials; h2h already biased)
    ln_lstm<<<B, 256, 0, stream>>>(i2hb, h2hb, cx, P,
                                   g_ih, beta_ih, g_hh, beta_hh, g_ho, beta_ho,
                                   hy, cyo, H, B);
}

// Round 16
// 123.617 us; speedup vs baseline: 6.7863x; 1.0570x over previous
//
#include <hip/hip_runtime.h>
#include <hip/hip_bf16.h>
#include <stdint.h>

typedef __attribute__((ext_vector_type(8))) short bf16x8;
typedef __attribute__((ext_vector_type(4))) float f32x4;

#define LN_EPS 1e-5f
#define KP 1056          // padded K = 33*32 (bias column at 1024)
#define GNT 33           // KP/32

// ---------------- helpers ----------------
__device__ inline unsigned f2bf(float f) {
    unsigned u = __builtin_bit_cast(unsigned, f);
    u += 0x7fffu + ((u >> 16) & 1u);          // RNE
    return u >> 16;
}
__device__ inline float bf2f(unsigned u) {
    return __builtin_bit_cast(float, u << 16);
}
__device__ inline float sigf(float x) {
    return 1.0f / (1.0f + __expf(-x));
}
__device__ inline float tanh_fast(float x) {
    return __builtin_fmaf(2.0f, 1.0f / (1.0f + __expf(-2.0f * x)), -1.0f);
}
__device__ inline float wred(float v) {
#pragma unroll
    for (int o = 32; o > 0; o >>= 1) v += __shfl_xor(v, o);
    return v;
}
__device__ inline void gload_lds16(const void* g, void* l) {
    __builtin_amdgcn_global_load_lds(
        (const __attribute__((address_space(1))) void*)g,
        (__attribute__((address_space(3))) void*)l, 16, 0, 0);
}

// ---------------- cast f32 -> bf16 into K-augmented buffers ----------------
// Region 1 (hx):  col 1024 = 1.0 ; Region 3 (w_hh): col 1024 = b_hh[row].
__global__ __launch_bounds__(256) void cast_aug(
    const float* __restrict__ inputs, const float* __restrict__ hx,
    const float* __restrict__ w_ih,   const float* __restrict__ w_hh,
    const float* __restrict__ b_hh,
    unsigned short* __restrict__ Abf, unsigned short* __restrict__ Hbf,
    unsigned short* __restrict__ Wih, unsigned short* __restrict__ Whh)
{
    const int CPR = 132;                       // 8-elem chunks per 1056-row
    const int PERREG = 4096 * CPR;
    int j = blockIdx.x * blockDim.x + threadIdx.x;
    const int r = j / PERREG;
    if (r >= 4) return;
    const int rem = j - r * PERREG;
    const int row = rem / CPR;
    const int c8  = rem - row * CPR;

    const float* src; unsigned short* dst;
    switch (r) {
        case 0: src = inputs; dst = Abf; break;
        case 1: src = hx;     dst = Hbf; break;
        case 2: src = w_ih;   dst = Wih; break;
        default: src = w_hh;  dst = Whh; break;
    }

    uint4 v;
    if (c8 < 128) {
        const float4* sp = reinterpret_cast<const float4*>(src + (size_t)row * 1024 + c8 * 8);
        float4 a = sp[0], b = sp[1];
        v.x = f2bf(a.x) | (f2bf(a.y) << 16);
        v.y = f2bf(a.z) | (f2bf(a.w) << 16);
        v.z = f2bf(b.x) | (f2bf(b.y) << 16);
        v.w = f2bf(b.z) | (f2bf(b.w) << 16);
    } else {
        v.x = v.y = v.z = v.w = 0u;
        if (c8 == 128) {
            if (r == 1) v.x = 0x3F80u;                    // bf16(1.0)
            else if (r == 3) v.x = f2bf(b_hh[row]);
        }
    }
    *reinterpret_cast<uint4*>(dst + (size_t)row * KP + c8 * 8) = v;
}

// =====================================================================
// 256x256 bf16 NT GEMM, K=1056 (bias-augmented for z=1). Ring-4 LDS,
// counted vmcnt, setprio, XOR chunk swizzle, bijective XCD swizzle.
// 16x16x32 MFMA, swapped operands: acc[f][n] = mfma(W[f], X[n]).
// Epilogue: LN stats on RAW f32 acc -> P[2][Bn][32]; pack + uint2 stores.
// (R11 configuration exactly — best measured total 124.4 us.)
// =====================================================================
__global__ __launch_bounds__(512) void gemm8p(
    const unsigned short* __restrict__ Aa, const unsigned short* __restrict__ Ba, unsigned short* __restrict__ Ca,
    const unsigned short* __restrict__ Ab, const unsigned short* __restrict__ Bb, unsigned short* __restrict__ Cb,
    float2* __restrict__ P,           // [2][Bn][32] per-row partials (bx*2+wr)
    int N, int Bn)
{
    __shared__ __attribute__((aligned(16))) short lds[65536];  // 128 KiB
    short* ldsA = lds;
    short* ldsB = lds + 32768;

    // ---- bijective XCD swizzle over 512 blocks ----
    const int gx  = gridDim.x;            // 16
    const int gxy = gx * gridDim.y;       // 256
    int bid = (blockIdx.z * gridDim.y + blockIdx.y) * gx + blockIdx.x;
    const int cpx = (gxy * gridDim.z) >> 3;   // 64
    int swz = (bid & 7) * cpx + (bid >> 3);
    const int z  = swz / gxy;
    const int r2 = swz - z * gxy;
    const int by = r2 / gx;
    const int bx = r2 - by * gx;

    const unsigned short* __restrict__ A = z ? Ab : Aa;   // batch [Bn,KP]
    const unsigned short* __restrict__ B = z ? Bb : Ba;   // weights [N,KP]
    unsigned short* __restrict__ C = z ? Cb : Ca;
    const int brow = by * 256, bcol = bx * 256;

    const int t    = threadIdx.x;
    const int lane = t & 63, w = t >> 6;
    const int wr = w >> 2, wc = w & 3;    // wr: gate half (128), wc: batch quarter (64)
    const int lr = lane & 15, kc = lane >> 4;

    // ---- staging addresses ----
    const int ci0 = t, ci1 = t + 512;
    const int r0 = ci0 >> 2, l0 = (ci0 & 3) ^ ((r0 >> 1) & 3);
    const int r1 = ci1 >> 2, l1 = (ci1 & 3) ^ ((r1 >> 1) & 3);
    const int gA0 = (brow + r0) * KP + l0 * 8;
    const int gA1 = (brow + r1) * KP + l1 * 8;
    const int gB0 = (bcol + r0) * KP + l0 * 8;
    const int gB1 = (bcol + r1) * KP + l1 * 8;
    const int d0 = ci0 * 8, d1 = ci1 * 8;

#define STAGE_A(u) { const int so_ = ((u) & 3) * 8192; \
    gload_lds16(A + gA0 + (u) * 32, ldsA + so_ + d0);  \
    gload_lds16(A + gA1 + (u) * 32, ldsA + so_ + d1); }
#define STAGE_B(u) { const int so_ = ((u) & 3) * 8192; \
    gload_lds16(B + gB0 + (u) * 32, ldsB + so_ + d0);  \
    gload_lds16(B + gB1 + (u) * 32, ldsB + so_ + d1); }

    // ---- ds_read offsets: W-frags (weights, 8) and X-frags (batch, 4) ----
    int offW[8], offX[4];
#pragma unroll
    for (int f = 0; f < 8; ++f) {
        int r = wr * 128 + f * 16 + lr;
        offW[f] = r * 32 + ((kc ^ ((r >> 1) & 3)) * 8);
    }
#pragma unroll
    for (int n = 0; n < 4; ++n) {
        int r = wc * 64 + n * 16 + lr;
        offX[n] = r * 32 + ((kc ^ ((r >> 1) & 3)) * 8);
    }

    f32x4 acc[8][4];
#pragma unroll
    for (int i = 0; i < 8; ++i)
#pragma unroll
        for (int j = 0; j < 4; ++j)
            acc[i][j] = (f32x4){0.f, 0.f, 0.f, 0.f};

    STAGE_A(0); STAGE_B(0); STAGE_A(1); STAGE_B(1); STAGE_A(2);
    asm volatile("s_waitcnt vmcnt(6)" ::: "memory");
    __builtin_amdgcn_s_barrier();

#pragma unroll 4
    for (int T = 0; T < GNT; ++T) {
        const int so = (T & 3) * 8192;
        bf16x8 w0, w1, w2, w3, x0, x1, x2, x3;

        // ---- phase 0: W-frags 0-3 x all X ----
        w0 = *(const bf16x8*)&ldsB[so + offW[0]];
        w1 = *(const bf16x8*)&ldsB[so + offW[1]];
        w2 = *(const bf16x8*)&ldsB[so + offW[2]];
        w3 = *(const bf16x8*)&ldsB[so + offW[3]];
        x0 = *(const bf16x8*)&ldsA[so + offX[0]];
        x1 = *(const bf16x8*)&ldsA[so + offX[1]];
        x2 = *(const bf16x8*)&ldsA[so + offX[2]];
        x3 = *(const bf16x8*)&ldsA[so + offX[3]];
        if (T + 2 < GNT) STAGE_B(T + 2);
        __builtin_amdgcn_s_barrier();
        asm volatile("s_waitcnt lgkmcnt(0)" ::: "memory");
        __builtin_amdgcn_sched_barrier(0);
        __builtin_amdgcn_s_setprio(1);
        acc[0][0] = __builtin_amdgcn_mfma_f32_16x16x32_bf16(w0, x0, acc[0][0], 0, 0, 0);
        acc[0][1] = __builtin_amdgcn_mfma_f32_16x16x32_bf16(w0, x1, acc[0][1], 0, 0, 0);
        acc[0][2] = __builtin_amdgcn_mfma_f32_16x16x32_bf16(w0, x2, acc[0][2], 0, 0, 0);
        acc[0][3] = __builtin_amdgcn_mfma_f32_16x16x32_bf16(w0, x3, acc[0][3], 0, 0, 0);
        acc[1][0] = __builtin_amdgcn_mfma_f32_16x16x32_bf16(w1, x0, acc[1][0], 0, 0, 0);
        acc[1][1] = __builtin_amdgcn_mfma_f32_16x16x32_bf16(w1, x1, acc[1][1], 0, 0, 0);
        acc[1][2] = __builtin_amdgcn_mfma_f32_16x16x32_bf16(w1, x2, acc[1][2], 0, 0, 0);
        acc[1][3] = __builtin_amdgcn_mfma_f32_16x16x32_bf16(w1, x3, acc[1][3], 0, 0, 0);
        acc[2][0] = __builtin_amdgcn_mfma_f32_16x16x32_bf16(w2, x0, acc[2][0], 0, 0, 0);
        acc[2][1] = __builtin_amdgcn_mfma_f32_16x16x32_bf16(w2, x1, acc[2][1], 0, 0, 0);
        acc[2][2] = __builtin_amdgcn_mfma_f32_16x16x32_bf16(w2, x2, acc[2][2], 0, 0, 0);
        acc[2][3] = __builtin_amdgcn_mfma_f32_16x16x32_bf16(w2, x3, acc[2][3], 0, 0, 0);
        acc[3][0] = __builtin_amdgcn_mfma_f32_16x16x32_bf16(w3, x0, acc[3][0], 0, 0, 0);
        acc[3][1] = __builtin_amdgcn_mfma_f32_16x16x32_bf16(w3, x1, acc[3][1], 0, 0, 0);
        acc[3][2] = __builtin_amdgcn_mfma_f32_16x16x32_bf16(w3, x2, acc[3][2], 0, 0, 0);
        acc[3][3] = __builtin_amdgcn_mfma_f32_16x16x32_bf16(w3, x3, acc[3][3], 0, 0, 0);
        __builtin_amdgcn_s_setprio(0);
        __builtin_amdgcn_s_barrier();

        // ---- phase 1: W-frags 4-7 x all X ----
        w0 = *(const bf16x8*)&ldsB[so + offW[4]];
        w1 = *(const bf16x8*)&ldsB[so + offW[5]];
        w2 = *(const bf16x8*)&ldsB[so + offW[6]];
        w3 = *(const bf16x8*)&ldsB[so + offW[7]];
        if (T + 3 < GNT) STAGE_A(T + 3);
        __builtin_amdgcn_s_barrier();
        asm volatile("s_waitcnt lgkmcnt(0)" ::: "memory");
        __builtin_amdgcn_sched_barrier(0);
        __builtin_amdgcn_s_setprio(1);
        acc[4][0] = __builtin_amdgcn_mfma_f32_16x16x32_bf16(w0, x0, acc[4][0], 0, 0, 0);
        acc[4][1] = __builtin_amdgcn_mfma_f32_16x16x32_bf16(w0, x1, acc[4][1], 0, 0, 0);
        acc[4][2] = __builtin_amdgcn_mfma_f32_16x16x32_bf16(w0, x2, acc[4][2], 0, 0, 0);
        acc[4][3] = __builtin_amdgcn_mfma_f32_16x16x32_bf16(w0, x3, acc[4][3], 0, 0, 0);
        acc[5][0] = __builtin_amdgcn_mfma_f32_16x16x32_bf16(w1, x0, acc[5][0], 0, 0, 0);
        acc[5][1] = __builtin_amdgcn_mfma_f32_16x16x32_bf16(w1, x1, acc[5][1], 0, 0, 0);
        acc[5][2] = __builtin_amdgcn_mfma_f32_16x16x32_bf16(w1, x2, acc[5][2], 0, 0, 0);
        acc[5][3] = __builtin_amdgcn_mfma_f32_16x16x32_bf16(w1, x3, acc[5][3], 0, 0, 0);
        acc[6][0] = __builtin_amdgcn_mfma_f32_16x16x32_bf16(w2, x0, acc[6][0], 0, 0, 0);
        acc[6][1] = __builtin_amdgcn_mfma_f32_16x16x32_bf16(w2, x1, acc[6][1], 0, 0, 0);
        acc[6][2] = __builtin_amdgcn_mfma_f32_16x16x32_bf16(w2, x2, acc[6][2], 0, 0, 0);
        acc[6][3] = __builtin_amdgcn_mfma_f32_16x16x32_bf16(w2, x3, acc[6][3], 0, 0, 0);
        acc[7][0] = __builtin_amdgcn_mfma_f32_16x16x32_bf16(w3, x0, acc[7][0], 0, 0, 0);
        acc[7][1] = __builtin_amdgcn_mfma_f32_16x16x32_bf16(w3, x1, acc[7][1], 0, 0, 0);
        acc[7][2] = __builtin_amdgcn_mfma_f32_16x16x32_bf16(w3, x2, acc[7][2], 0, 0, 0);
        acc[7][3] = __builtin_amdgcn_mfma_f32_16x16x32_bf16(w3, x3, acc[7][3], 0, 0, 0);
        __builtin_amdgcn_s_setprio(0);
        if (T < GNT - 3)      { asm volatile("s_waitcnt vmcnt(6)" ::: "memory"); }
        else if (T == GNT - 3){ asm volatile("s_waitcnt vmcnt(4)" ::: "memory"); }
        else if (T == GNT - 2){ asm volatile("s_waitcnt vmcnt(0)" ::: "memory"); }
        __builtin_amdgcn_s_barrier();
    }

    // ---- epilogue: stats on raw f32 acc + pack + uint2 stores ----
    const int gc0 = bcol + wr * 128 + kc * 4;
    const int mr0 = brow + wc * 64 + lr;

    float s[4] = {0.f, 0.f, 0.f, 0.f}, q[4] = {0.f, 0.f, 0.f, 0.f};
#pragma unroll
    for (int f = 0; f < 8; ++f) {
#pragma unroll
        for (int n = 0; n < 4; ++n) {
            float a0 = acc[f][n][0], a1 = acc[f][n][1];
            float a2 = acc[f][n][2], a3 = acc[f][n][3];
            s[n] += (a0 + a1) + (a2 + a3);
            q[n] += __builtin_fmaf(a0, a0, a1 * a1) + __builtin_fmaf(a2, a2, a3 * a3);
            unsigned u0 = f2bf(a0), u1 = f2bf(a1), u2 = f2bf(a2), u3 = f2bf(a3);
            uint2 pk; pk.x = u0 | (u1 << 16); pk.y = u2 | (u3 << 16);
            *reinterpret_cast<uint2*>(&C[(size_t)(mr0 + n * 16) * N + gc0 + f * 16]) = pk;
        }
    }
#pragma unroll
    for (int n = 0; n < 4; ++n) {
        s[n] += __shfl_xor(s[n], 16); s[n] += __shfl_xor(s[n], 32);
        q[n] += __shfl_xor(q[n], 16); q[n] += __shfl_xor(q[n], 32);
    }
    if (kc == 0) {
#pragma unroll
        for (int n = 0; n < 4; ++n) {
            float2 pr; pr.x = s[n]; pr.y = q[n];
            P[(size_t)(z * Bn + mr0 + n * 16) * 32 + bx * 2 + wr] = pr;
        }
    }
#undef STAGE_A
#undef STAGE_B
}

// ---------------- single-pass LN + LSTM (stats folded from P) ----------------
__global__ __launch_bounds__(256) void ln_lstm(
    const unsigned short* __restrict__ i2h,   // [B,4H] bf16
    const unsigned short* __restrict__ h2h,   // [B,4H] bf16 (bias included)
    const float* __restrict__ cx,
    const float2* __restrict__ P,             // [2][B][32] partial (sum,sumsq)
    const float* __restrict__ g_ih, const float* __restrict__ be_ih,
    const float* __restrict__ g_hh, const float* __restrict__ be_hh,
    const float* __restrict__ g_ho, const float* __restrict__ be_ho,
    float* __restrict__ hy, float* __restrict__ cy, int H, int B)
{
    const int b = blockIdx.x;
    const int t = threadIdx.x;
    const int lane = t & 63;
    const int wave = t >> 6;
    const int H4 = 4 * H;
    const int h0 = t * 4;

    const unsigned short* xi = i2h + (size_t)b * H4;
    const unsigned short* xh = h2h + (size_t)b * H4;

    __shared__ float red[4][2];
    __shared__ float st[4];   // mI, rI, mH, rH

    if (wave == 0) {
        const int half = lane >> 5;               // 0: i2h, 1: h2h
        float2 v = P[((size_t)half * B + b) * 32 + (lane & 31)];
        v.x += __shfl_xor(v.x, 1);  v.y += __shfl_xor(v.y, 1);
        v.x += __shfl_xor(v.x, 2);  v.y += __shfl_xor(v.y, 2);
        v.x += __shfl_xor(v.x, 4);  v.y += __shfl_xor(v.y, 4);
        v.x += __shfl_xor(v.x, 8);  v.y += __shfl_xor(v.y, 8);
        v.x += __shfl_xor(v.x, 16); v.y += __shfl_xor(v.y, 16);
        if ((lane & 31) == 0) {
            const float inv4H = 1.0f / (float)H4;
            float m = v.x * inv4H;
            float r = rsqrtf(v.y * inv4H - m * m + LN_EPS);
            st[half * 2]     = m;
            st[half * 2 + 1] = r;
        }
    }
    __syncthreads();
    const float mI = st[0], rI = st[1], mH = st[2], rH = st[3];

    float gate[4][4];
#pragma unroll
    for (int q = 0; q < 4; ++q) {
        const int j = q * H + h0;
        ushort4 vi = *reinterpret_cast<const ushort4*>(&xi[j]);
        ushort4 vh = *reinterpret_cast<const ushort4*>(&xh[j]);
        float4 gi = *reinterpret_cast<const float4*>(&g_ih[j]);
        float4 bi = *reinterpret_cast<const float4*>(&be_ih[j]);
        float4 gh = *reinterpret_cast<const float4*>(&g_hh[j]);
        float4 bh = *reinterpret_cast<const float4*>(&be_hh[j]);
        gate[q][0] = (bf2f(vi.x) - mI) * rI * gi.x + bi.x + (bf2f(vh.x) - mH) * rH * gh.x + bh.x;
        gate[q][1] = (bf2f(vi.y) - mI) * rI * gi.y + bi.y + (bf2f(vh.y) - mH) * rH * gh.y + bh.y;
        gate[q][2] = (bf2f(vi.z) - mI) * rI * gi.z + bi.z + (bf2f(vh.z) - mH) * rH * gh.z + bh.z;
        gate[q][3] = (bf2f(vi.w) - mI) * rI * gi.w + bi.w + (bf2f(vh.w) - mH) * rH * gh.w + bh.w;
    }

    float4 cxv = *reinterpret_cast<const float4*>(&cx[(size_t)b * H + h0]);
    float cvals[4] = {cxv.x, cxv.y, cxv.z, cxv.w};
    float tv[4], ov[4];
    float s2 = 0.f, q2 = 0.f;
    float4 cyv;
#pragma unroll
    for (int k = 0; k < 4; ++k) {
        float c = sigf(gate[1][k]) * cvals[k] + sigf(gate[0][k]) * tanh_fast(gate[3][k]);
        ((float*)&cyv)[k] = c;
        float tc = tanh_fast(c);
        tv[k] = tc; ov[k] = sigf(gate[2][k]);
        s2 += tc; q2 += tc * tc;
    }
    *reinterpret_cast<float4*>(&cy[(size_t)b * H + h0]) = cyv;

    s2 = wred(s2); q2 = wred(q2);
    if (lane == 0) { red[wave][0] = s2; red[wave][1] = q2; }
    __syncthreads();
    float S2 = red[0][0] + red[1][0] + red[2][0] + red[3][0];
    float Q2 = red[0][1] + red[1][1] + red[2][1] + red[3][1];
    const float invH = 1.0f / (float)H;
    float mt = S2 * invH;
    float rt = rsqrtf(Q2 * invH - mt * mt + LN_EPS);

    float4 go = *reinterpret_cast<const float4*>(&g_ho[h0]);
    float4 bo = *reinterpret_cast<const float4*>(&be_ho[h0]);
    float4 hyv;
    hyv.x = ov[0] * ((tv[0] - mt) * rt * go.x + bo.x);
    hyv.y = ov[1] * ((tv[1] - mt) * rt * go.y + bo.y);
    hyv.z = ov[2] * ((tv[2] - mt) * rt * go.z + bo.z);
    hyv.w = ov[3] * ((tv[3] - mt) * rt * go.w + bo.w);
    *reinterpret_cast<float4*>(&hy[(size_t)b * H + h0]) = hyv;
}

// ---------------- launcher ----------------
extern "C" void kernel_launch(void* const* d_in, const int* in_sizes, int n_in,
                              void* d_out, int out_size, void* d_ws, size_t ws_size,
                              hipStream_t stream) {
    const float* inputs  = (const float*)d_in[0];
    const float* hx      = (const float*)d_in[1];
    const float* cx      = (const float*)d_in[2];
    const float* w_ih    = (const float*)d_in[3];
    const float* w_hh    = (const float*)d_in[4];
    const float* b_hh    = (const float*)d_in[5];
    const float* g_ih    = (const float*)d_in[6];
    const float* beta_ih = (const float*)d_in[7];
    const float* g_hh    = (const float*)d_in[8];
    const float* beta_hh = (const float*)d_in[9];
    const float* g_ho    = (const float*)d_in[10];
    const float* beta_ho = (const float*)d_in[11];

    const int H  = in_sizes[10];            // 1024
    const int B  = in_sizes[1] / H;         // 4096
    const int H4 = 4 * H;

    uint8_t* ws = (uint8_t*)d_ws;
    size_t off = 0;
    unsigned short* Abf = (unsigned short*)(ws + off); off += (size_t)B * KP * 2;
    unsigned short* Hbf = (unsigned short*)(ws + off); off += (size_t)B * KP * 2;
    unsigned short* Wih = (unsigned short*)(ws + off); off += (size_t)H4 * KP * 2;
    unsigned short* Whh = (unsigned short*)(ws + off); off += (size_t)H4 * KP * 2;
    unsigned short* i2hb = (unsigned short*)(ws + off); off += (size_t)B * H4 * 2;
    unsigned short* h2hb = (unsigned short*)(ws + off); off += (size_t)B * H4 * 2;
    float2* P   = (float2*)(ws + off); off += (size_t)2 * B * 32 * sizeof(float2);

    float* hy  = (float*)d_out;
    float* cyo = (float*)d_out + (size_t)B * H;

    // 1) casts into K-augmented buffers (bias baked into Hbf/Whh)
    {
        const int tot = 4 * 4096 * 132;
        cast_aug<<<(tot + 255) / 256, 256, 0, stream>>>(
            inputs, hx, w_ih, w_hh, b_hh, Abf, Hbf, Wih, Whh);
    }

    // 2) both GEMMs (K=1056) + raw-f32 LN-stat partials
    {
        dim3 grid(H4 / 256, B / 256, 2);
        gemm8p<<<grid, 512, 0, stream>>>(Abf, Wih, i2hb, Hbf, Whh, h2hb, P, H4, B);
    }

    // 3) single-pass LN + LSTM (folds partials; h2h already biased)
    ln_lstm<<<B, 256, 0, stream>>>(i2hb, h2hb, cx, P,
                                   g_ih, beta_ih, g_hh, beta_hh, g_ho, beta_ho,
                                   hy, cyo, H, B);
}